// Round 12
// baseline (174.978 us; speedup 1.0000x reference)
//
#include <hip/hip_runtime.h>
#include <math.h>

#define NROWS 131072
#define XC    17      // FLOW_SIZE+1
#define ROWSB 128     // rows per block
#define HID   256
#define NB    128
#define NCOL  1024
#define LOG2E 1.44269504088896340736f

typedef __attribute__((ext_vector_type(8))) short bf16x8;
typedef __attribute__((ext_vector_type(4))) float f32x4;

#if __has_builtin(__builtin_amdgcn_exp2f)
#define EXP2F(v) __builtin_amdgcn_exp2f(v)
#else
#define EXP2F(v) exp2f(v)
#endif
#if __has_builtin(__builtin_amdgcn_rcpf)
#define RCPF(v) __builtin_amdgcn_rcpf(v)
#else
#define RCPF(v) (1.f / (v))
#endif

__device__ __forceinline__ unsigned short f2bf(float f) {
    unsigned int u = __float_as_uint(f);
    return (unsigned short)((u + 0x7FFFu + ((u >> 16) & 1u)) >> 16);  // RNE
}

// 16-lane reduction on the VALU via DPP (validated; no LDS-pipe traffic).
__device__ __forceinline__ float red16(float v) {
    int x;
    x = __builtin_amdgcn_update_dpp(0, __float_as_int(v), 0xB1, 0xF, 0xF, true);
    v += __int_as_float(x);
    x = __builtin_amdgcn_update_dpp(0, __float_as_int(v), 0x4E, 0xF, 0xF, true);
    v += __int_as_float(x);
    x = __builtin_amdgcn_update_dpp(0, __float_as_int(v), 0x141, 0xF, 0xF, true);
    v += __int_as_float(x);
    x = __builtin_amdgcn_update_dpp(0, __float_as_int(v), 0x140, 0xF, 0xF, true);
    v += __int_as_float(x);
    return v;
}

// W2 [256][1024] fp32 -> w2t [col][k-swizzled] bf16 * log2(e). (validated R5/R7)
__global__ void prep_w2(const float* __restrict__ W2, unsigned short* __restrict__ w2t) {
    const int g   = blockIdx.x * 256 + threadIdx.x;   // 32768 threads
    const int col = g >> 5, go = g & 31;              // granule go of col
    const int kg  = (go & ~7) | ((go & 7) ^ (col & 7));  // source k-granule
    unsigned int p[4];
    #pragma unroll
    for (int j = 0; j < 4; ++j) {
        const unsigned short lo = f2bf(W2[(size_t)(kg * 8 + 2 * j) * NCOL + col] * LOG2E);
        const unsigned short hi = f2bf(W2[(size_t)(kg * 8 + 2 * j + 1) * NCOL + col] * LOG2E);
        p[j] = (unsigned int)lo | ((unsigned int)hi << 16);
    }
    *(uint4*)&w2t[(size_t)col * HID + go * 8] = make_uint4(p[0], p[1], p[2], p[3]);
}

__global__ __launch_bounds__(256, 2)
void gplc11(const float* __restrict__ x,
            const float* __restrict__ W1,
            const float* __restrict__ b1,
            const unsigned short* __restrict__ w2t,
            const float* __restrict__ b2,
            float* __restrict__ out)
{
    __shared__ float xs[ROWSB * XC];                       // 8704 B
    __shared__ __align__(16) union {
        unsigned short hb[ROWSB * HID];                    // 64 KB (phase 1 + A-frag load)
        struct { unsigned short w2[3][NB * 64]; float b2s[NCOL]; } g;  // 48+4 KB (t-loop)
    } u;                                                   // total 74240 B -> 2 blocks/CU

    const int tid  = threadIdx.x;
    const int lane = tid & 63;
    const int w    = tid >> 6;        // wave 0..3 -> rows w*32..w*32+31
    const int quad = lane >> 4;
    const int l15  = lane & 15;
    const int wr   = w * 32;
    const int ksw  = (lane & 7) << 3; // B-frag k swizzle (validated: 0 conflicts)
    const size_t r0 = (size_t)blockIdx.x * ROWSB;

    // stage x tile; W1 columns + b1 straight from L2 into regs
    for (int i = tid; i < ROWSB * XC; i += 256) xs[i] = x[r0 * XC + i];
    const int cp = tid & 127, hlf = tid >> 7;
    float w1r[16];
    #pragma unroll
    for (int i = 0; i < 8; ++i) {
        const float2 t2 = *(const float2*)&W1[i * HID + 2 * cp];
        w1r[2 * i] = t2.x; w1r[2 * i + 1] = t2.y;
    }
    const float2 b1v = *(const float2*)&b1[2 * cp];
    __syncthreads();

    // ---- phase 1: h = relu(xA@W1+b1) -> bf16 LDS, granule-XOR row swizzle
    for (int r = 0; r < 64; ++r) {
        const int row = hlf * 64 + r;
        float a0 = b1v.x, a1 = b1v.y;
        #pragma unroll
        for (int i = 0; i < 8; ++i) {
            const float xv = xs[row * XC + i];
            a0 = fmaf(xv, w1r[2 * i], a0);
            a1 = fmaf(xv, w1r[2 * i + 1], a1);
        }
        a0 = fmaxf(a0, 0.f); a1 = fmaxf(a1, 0.f);
        const int eidx = row * HID + (((cp >> 2) ^ (row & 15)) << 3) + ((cp & 3) << 1);
        *(unsigned int*)&u.hb[eidx] = (unsigned int)f2bf(a0) | ((unsigned int)f2bf(a1) << 16);
    }
    __syncthreads();

    // ---- A-fragment register cache: 32 rows x 256 K per wave (64 VGPR).
    // ALL indices compile-time (dynamic idx / conditional init -> scratch spill).
    bf16x8 afr[2][8];
    #pragma unroll
    for (int rt = 0; rt < 2; ++rt)
        #pragma unroll
        for (int kf = 0; kf < 8; ++kf) {
            const int row = wr + rt * 16 + l15;    // row&15 == l15
            afr[rt][kf] = *(const bf16x8*)&u.hb[row * HID + (((kf * 4 + quad) ^ l15) << 3)];
        }
    __syncthreads();   // hb dead; union region becomes w2 triple-buffer + b2s

    for (int i = tid; i < NCOL; i += 256) u.g.b2s[i] = b2[i] * LOG2E;

    // stage K-chunk n (t=n>>2, kc=n&3) into buffer n%3: 16 KB linear DMA copy
    auto stage = [&](int n) {
        const int t = n >> 2, kc = n & 3, buf = n % 3;   // LDS idx may be dynamic
        #pragma unroll
        for (int j = 0; j < 4; ++j) {
            const int ob = (w * 4 + j) * 512;              // wave-uniform LDS base
            const int c  = (ob >> 6) + (lane >> 3);        // local col 0..127
            const int kl = (lane & 7) << 3;
            const unsigned short* gp = w2t + (size_t)(t * NB + c) * HID + kc * 64 + kl;
            unsigned short* lp = &u.g.w2[buf][ob];
            __builtin_amdgcn_global_load_lds(
                (const __attribute__((address_space(1))) unsigned int*)gp,
                (__attribute__((address_space(3))) unsigned int*)lp, 16, 0, 0);
        }
    };

    float jf[2][4] = {{1.f,1.f,1.f,1.f},{1.f,1.f,1.f,1.f}};

    // 2-deep prefetch prologue: at every barrier below, the only outstanding
    // DMA is >=1 full iteration old -> the compiler's vmcnt(0) drain is free.
    stage(0);
    stage(1);
    #pragma unroll 1
    for (int t = 0; t < 8; ++t) {
        f32x4 acc[2][8];
        #pragma unroll
        for (int rt = 0; rt < 2; ++rt)
            #pragma unroll
            for (int ct = 0; ct < 8; ++ct) acc[rt][ct] = (f32x4){0.f, 0.f, 0.f, 0.f};

        #pragma unroll
        for (int kc = 0; kc < 4; ++kc) {          // STATIC unroll -> static afr idx
            const int n = t * 4 + kc;
            __syncthreads();                       // chunk n staged (1 iter ago); buf n%3 free of prev readers
            if (n + 2 < 32) stage(n + 2);          // prefetch AFTER the barrier
            const unsigned short* wsb = u.g.w2[n % 3];
            #pragma unroll
            for (int ks = 0; ks < 2; ++ks) {
                const int kf = kc * 2 + ks;        // compile-time
                const int klog = ks * 32 + quad * 8;
                #pragma unroll
                for (int ct = 0; ct < 8; ++ct) {
                    const int c = ct * 16 + l15;
                    const bf16x8 bf = *(const bf16x8*)&wsb[c * 64 + (klog ^ ksw)];
                    acc[0][ct] = __builtin_amdgcn_mfma_f32_16x16x32_bf16(afr[0][kf], bf, acc[0][ct], 0, 0, 0);
                    acc[1][ct] = __builtin_amdgcn_mfma_f32_16x16x32_bf16(afr[1][kf], bf, acc[1][ct], 0, 0, 0);
                }
            }
        }

        // ---- fused epilogue for transform t (wave covers full 128-col row)
        float bb[8];
        #pragma unroll
        for (int ct = 0; ct < 8; ++ct) bb[ct] = u.g.b2s[t * NB + ct * 16 + l15];
        #pragma unroll
        for (int rt = 0; rt < 2; ++rt)
            #pragma unroll
            for (int i = 0; i < 4; ++i) {
                const int row = wr + rt * 16 + quad * 4 + i;
                const float alpha = xs[row * XC + 8 + t] * 128.f;   // broadcast
                const float fb = floorf(alpha);
                const int bin = min(max((int)fb, 0), 127);
                const float fr = alpha - fb;
                float e[8];
                #pragma unroll
                for (int ct = 0; ct < 8; ++ct) e[ct] = EXP2F(acc[rt][ct][i] + bb[ct]);
                const float P1 = e[0],      P2 = P1 + e[1], P3 = P2 + e[2], P4 = P3 + e[3];
                const float P5 = P4 + e[4], P6 = P5 + e[5], P7 = P6 + e[6], P8 = P7 + e[7];
                int thr = (bin - l15 + 15) >> 4;           // ceil((bin-l15)/16)
                thr = min(max(thr, 0), 8);
                const float sA = (thr & 1) ? P1 : 0.f;
                const float sB = (thr & 1) ? P3 : P2;
                const float sC = (thr & 1) ? P5 : P4;
                const float sD = (thr & 1) ? P7 : P6;
                const float sE = (thr & 2) ? sB : sA;
                const float sF = (thr & 2) ? sD : sC;
                float num = (thr & 4) ? sF : sE;
                num = (thr >= 8) ? P8 : num;
                const int cb = bin >> 4;
                const float t1 = (cb & 1) ? e[1] : e[0];
                const float t2 = (cb & 1) ? e[3] : e[2];
                const float t3 = (cb & 1) ? e[5] : e[4];
                const float t4 = (cb & 1) ? e[7] : e[6];
                const float u1 = (cb & 2) ? t2 : t1;
                const float u2 = (cb & 2) ? t4 : t3;
                const float es = (cb & 4) ? u2 : u1;
                float eb  = ((bin & 15) == l15) ? es : 0.f;
                float tot = P8;
                tot = red16(tot); num = red16(num); eb = red16(eb);
                const float inv = RCPF(tot);
                jf[rt][i] *= 128.f * eb * inv;
                if (l15 == 0) xs[row * XC + 8 + t] = fmaf(eb, fr, num) * inv;
            }
    }

    // jacobian into xs, then one fully-coalesced block copy-out
    if (l15 == 0) {
        #pragma unroll
        for (int rt = 0; rt < 2; ++rt)
            #pragma unroll
            for (int i = 0; i < 4; ++i) {
                const int row = wr + rt * 16 + quad * 4 + i;
                xs[row * XC + 16] *= jf[rt][i];
            }
    }
    __syncthreads();
    for (int i = tid; i < ROWSB * XC; i += 256) out[r0 * XC + i] = xs[i];
}

extern "C" void kernel_launch(void* const* d_in, const int* in_sizes, int n_in,
                              void* d_out, int out_size, void* d_ws, size_t ws_size,
                              hipStream_t stream) {
    (void)in_sizes; (void)n_in; (void)ws_size; (void)out_size;
    prep_w2<<<(NCOL * HID / 8) / 256, 256, 0, stream>>>(
        (const float*)d_in[3], (unsigned short*)d_ws);
    gplc11<<<NROWS / ROWSB, 256, 0, stream>>>(
        (const float*)d_in[0], (const float*)d_in[1], (const float*)d_in[2],
        (const unsigned short*)d_ws, (const float*)d_in[4], (float*)d_out);
}

// Round 13
// 173.949 us; speedup vs baseline: 1.0059x; 1.0059x over previous
//
#include <hip/hip_runtime.h>
#include <math.h>

#define NROWS 131072
#define XC    17      // FLOW_SIZE+1
#define ROWSB 128     // rows per block
#define HID   256
#define NB    128
#define NCOL  1024
#define LOG2E 1.44269504088896340736f

typedef __attribute__((ext_vector_type(8))) short bf16x8;
typedef __attribute__((ext_vector_type(4))) float f32x4;

#if __has_builtin(__builtin_amdgcn_exp2f)
#define EXP2F(v) __builtin_amdgcn_exp2f(v)
#else
#define EXP2F(v) exp2f(v)
#endif
#if __has_builtin(__builtin_amdgcn_rcpf)
#define RCPF(v) __builtin_amdgcn_rcpf(v)
#else
#define RCPF(v) (1.f / (v))
#endif

__device__ __forceinline__ unsigned short f2bf(float f) {
    unsigned int u = __float_as_uint(f);
    return (unsigned short)((u + 0x7FFFu + ((u >> 16) & 1u)) >> 16);  // RNE
}

// 16-lane reduction on the VALU via DPP (validated; no LDS-pipe traffic).
__device__ __forceinline__ float red16(float v) {
    int x;
    x = __builtin_amdgcn_update_dpp(0, __float_as_int(v), 0xB1, 0xF, 0xF, true);
    v += __int_as_float(x);
    x = __builtin_amdgcn_update_dpp(0, __float_as_int(v), 0x4E, 0xF, 0xF, true);
    v += __int_as_float(x);
    x = __builtin_amdgcn_update_dpp(0, __float_as_int(v), 0x141, 0xF, 0xF, true);
    v += __int_as_float(x);
    x = __builtin_amdgcn_update_dpp(0, __float_as_int(v), 0x140, 0xF, 0xF, true);
    v += __int_as_float(x);
    return v;
}

// R13: coalesced LDS-transpose prep. Old prep did 8 scalar 4B loads at 4KB
// stride per thread (latency-bound, ~30-40us of the 45us total-vs-kernel gap).
// Each block: 64k x 32col tile. Phase A: float4 row-major loads (coalesced),
// bf16 k-pair pack into padded LDS. Phase B: one 16B granule store per thread
// with the validated granule-XOR swizzle: (g^(c&7))*8+j == (k&63)^((col&7)<<3).
__global__ void prep_w2(const float* __restrict__ W2, unsigned short* __restrict__ w2t) {
    __shared__ __align__(16) unsigned short tkT[32][80];  // [col][k], stride 160B
    const int tid = threadIdx.x;
    const int k0 = (blockIdx.x & 3) * 64;
    const int c0 = (blockIdx.x >> 2) * 32;
    const int c4 = (tid & 7) * 4;        // 4-col group
    const int kk = (tid >> 3) * 2;       // k-pair
    const float4 r0 = *(const float4*)&W2[(size_t)(k0 + kk) * NCOL + c0 + c4];
    const float4 r1 = *(const float4*)&W2[(size_t)(k0 + kk + 1) * NCOL + c0 + c4];
    const float v0[4] = {r0.x, r0.y, r0.z, r0.w};
    const float v1[4] = {r1.x, r1.y, r1.z, r1.w};
    #pragma unroll
    for (int i = 0; i < 4; ++i) {
        const unsigned int p = (unsigned int)f2bf(v0[i] * LOG2E)
                             | ((unsigned int)f2bf(v1[i] * LOG2E) << 16);
        *(unsigned int*)&tkT[c4 + i][kk] = p;
    }
    __syncthreads();
    const int g = tid & 7, c = tid >> 3;
    const uint4 q = *(const uint4*)&tkT[c][g * 8];
    *(uint4*)&w2t[(size_t)(c0 + c) * HID + k0 + ((g ^ (c & 7)) << 3)] = q;
}

// Main kernel: byte-identical to R7's validated gplc6 (125us plateau).
__global__ __launch_bounds__(256, 2)
void gplc6(const float* __restrict__ x,
           const float* __restrict__ W1,
           const float* __restrict__ b1,
           const unsigned short* __restrict__ w2t,
           const float* __restrict__ b2,
           float* __restrict__ out)
{
    __shared__ float xs[ROWSB * XC];                       // 8704 B
    __shared__ __align__(16) union {
        unsigned short hb[ROWSB * HID];                    // 64 KB (phase 1 + A-frag load)
        struct { unsigned short w2[2][NB * 64]; float b2s[NCOL]; } g;  // 36 KB (t-loop)
    } u;                                                   // total 74240 B -> 2 blocks/CU

    const int tid  = threadIdx.x;
    const int lane = tid & 63;
    const int w    = tid >> 6;        // wave 0..3 -> rows w*32..w*32+31
    const int quad = lane >> 4;
    const int l15  = lane & 15;
    const int wr   = w * 32;
    const int ksw  = (lane & 7) << 3; // B-frag k swizzle (validated: 0 conflicts)
    const size_t r0 = (size_t)blockIdx.x * ROWSB;

    for (int i = tid; i < ROWSB * XC; i += 256) xs[i] = x[r0 * XC + i];
    const int cp = tid & 127, hlf = tid >> 7;
    float w1r[16];
    #pragma unroll
    for (int i = 0; i < 8; ++i) {
        const float2 t2 = *(const float2*)&W1[i * HID + 2 * cp];
        w1r[2 * i] = t2.x; w1r[2 * i + 1] = t2.y;
    }
    const float2 b1v = *(const float2*)&b1[2 * cp];
    __syncthreads();

    // ---- phase 1: h = relu(xA@W1+b1) -> bf16 LDS, granule-XOR row swizzle
    for (int r = 0; r < 64; ++r) {
        const int row = hlf * 64 + r;
        float a0 = b1v.x, a1 = b1v.y;
        #pragma unroll
        for (int i = 0; i < 8; ++i) {
            const float xv = xs[row * XC + i];
            a0 = fmaf(xv, w1r[2 * i], a0);
            a1 = fmaf(xv, w1r[2 * i + 1], a1);
        }
        a0 = fmaxf(a0, 0.f); a1 = fmaxf(a1, 0.f);
        const int eidx = row * HID + (((cp >> 2) ^ (row & 15)) << 3) + ((cp & 3) << 1);
        *(unsigned int*)&u.hb[eidx] = (unsigned int)f2bf(a0) | ((unsigned int)f2bf(a1) << 16);
    }
    __syncthreads();

    // ---- A-fragment register cache: 32 rows x 256 K per wave (64 VGPR).
    bf16x8 afr[2][8];
    #pragma unroll
    for (int rt = 0; rt < 2; ++rt)
        #pragma unroll
        for (int kf = 0; kf < 8; ++kf) {
            const int row = wr + rt * 16 + l15;    // row&15 == l15
            afr[rt][kf] = *(const bf16x8*)&u.hb[row * HID + (((kf * 4 + quad) ^ l15) << 3)];
        }
    __syncthreads();   // hb dead; union region becomes w2 dbuf + b2s

    for (int i = tid; i < NCOL; i += 256) u.g.b2s[i] = b2[i] * LOG2E;

    auto stage = [&](int n) {
        const int t = n >> 2, kc = n & 3, buf = n & 1;
        #pragma unroll
        for (int j = 0; j < 4; ++j) {
            const int ob = (w * 4 + j) * 512;              // wave-uniform LDS base
            const int c  = (ob >> 6) + (lane >> 3);        // local col 0..127
            const int kl = (lane & 7) << 3;
            const unsigned short* gp = w2t + (size_t)(t * NB + c) * HID + kc * 64 + kl;
            unsigned short* lp = &u.g.w2[buf][ob];
            __builtin_amdgcn_global_load_lds(
                (const __attribute__((address_space(1))) unsigned int*)gp,
                (__attribute__((address_space(3))) unsigned int*)lp, 16, 0, 0);
        }
    };

    float jf[2][4] = {{1.f,1.f,1.f,1.f},{1.f,1.f,1.f,1.f}};

    stage(0);
    #pragma unroll 1
    for (int t = 0; t < 8; ++t) {
        f32x4 acc[2][8];
        #pragma unroll
        for (int rt = 0; rt < 2; ++rt)
            #pragma unroll
            for (int ct = 0; ct < 8; ++ct) acc[rt][ct] = (f32x4){0.f, 0.f, 0.f, 0.f};

        #pragma unroll
        for (int kc = 0; kc < 4; ++kc) {          // STATIC unroll -> static afr idx
            __syncthreads();                       // chunk staged; prev buf readers done
            const int n = t * 4 + kc;
            if (n < 31) stage(n + 1);
            const unsigned short* wsb = u.g.w2[kc & 1];
            #pragma unroll
            for (int ks = 0; ks < 2; ++ks) {
                const int kf = kc * 2 + ks;        // compile-time
                const int klog = ks * 32 + quad * 8;
                #pragma unroll
                for (int ct = 0; ct < 8; ++ct) {
                    const int c = ct * 16 + l15;
                    const bf16x8 bf = *(const bf16x8*)&wsb[c * 64 + (klog ^ ksw)];
                    acc[0][ct] = __builtin_amdgcn_mfma_f32_16x16x32_bf16(afr[0][kf], bf, acc[0][ct], 0, 0, 0);
                    acc[1][ct] = __builtin_amdgcn_mfma_f32_16x16x32_bf16(afr[1][kf], bf, acc[1][ct], 0, 0, 0);
                }
            }
        }

        // ---- fused epilogue for transform t (wave covers full 128-col row)
        float bb[8];
        #pragma unroll
        for (int ct = 0; ct < 8; ++ct) bb[ct] = u.g.b2s[t * NB + ct * 16 + l15];
        #pragma unroll
        for (int rt = 0; rt < 2; ++rt)
            #pragma unroll
            for (int i = 0; i < 4; ++i) {
                const int row = wr + rt * 16 + quad * 4 + i;
                const float alpha = xs[row * XC + 8 + t] * 128.f;   // broadcast
                const float fb = floorf(alpha);
                const int bin = min(max((int)fb, 0), 127);
                const float fr = alpha - fb;
                float e[8];
                #pragma unroll
                for (int ct = 0; ct < 8; ++ct) e[ct] = EXP2F(acc[rt][ct][i] + bb[ct]);
                const float P1 = e[0],      P2 = P1 + e[1], P3 = P2 + e[2], P4 = P3 + e[3];
                const float P5 = P4 + e[4], P6 = P5 + e[5], P7 = P6 + e[6], P8 = P7 + e[7];
                int thr = (bin - l15 + 15) >> 4;           // ceil((bin-l15)/16)
                thr = min(max(thr, 0), 8);
                const float sA = (thr & 1) ? P1 : 0.f;
                const float sB = (thr & 1) ? P3 : P2;
                const float sC = (thr & 1) ? P5 : P4;
                const float sD = (thr & 1) ? P7 : P6;
                const float sE = (thr & 2) ? sB : sA;
                const float sF = (thr & 2) ? sD : sC;
                float num = (thr & 4) ? sF : sE;
                num = (thr >= 8) ? P8 : num;
                const int cb = bin >> 4;
                const float t1 = (cb & 1) ? e[1] : e[0];
                const float t2 = (cb & 1) ? e[3] : e[2];
                const float t3 = (cb & 1) ? e[5] : e[4];
                const float t4 = (cb & 1) ? e[7] : e[6];
                const float u1 = (cb & 2) ? t2 : t1;
                const float u2 = (cb & 2) ? t4 : t3;
                const float es = (cb & 4) ? u2 : u1;
                float eb  = ((bin & 15) == l15) ? es : 0.f;
                float tot = P8;
                tot = red16(tot); num = red16(num); eb = red16(eb);
                const float inv = RCPF(tot);
                jf[rt][i] *= 128.f * eb * inv;
                if (l15 == 0) xs[row * XC + 8 + t] = fmaf(eb, fr, num) * inv;
            }
    }

    // jacobian into xs, then one fully-coalesced block copy-out
    if (l15 == 0) {
        #pragma unroll
        for (int rt = 0; rt < 2; ++rt)
            #pragma unroll
            for (int i = 0; i < 4; ++i) {
                const int row = wr + rt * 16 + quad * 4 + i;
                xs[row * XC + 16] *= jf[rt][i];
            }
    }
    __syncthreads();
    for (int i = tid; i < ROWSB * XC; i += 256) out[r0 * XC + i] = xs[i];
}

extern "C" void kernel_launch(void* const* d_in, const int* in_sizes, int n_in,
                              void* d_out, int out_size, void* d_ws, size_t ws_size,
                              hipStream_t stream) {
    (void)in_sizes; (void)n_in; (void)ws_size; (void)out_size;
    prep_w2<<<128, 256, 0, stream>>>((const float*)d_in[3], (unsigned short*)d_ws);
    gplc6<<<NROWS / ROWSB, 256, 0, stream>>>(
        (const float*)d_in[0], (const float*)d_in[1], (const float*)d_in[2],
        (const unsigned short*)d_ws, (const float*)d_in[4], (float*)d_out);
}